// Round 3
// baseline (12107.973 us; speedup 1.0000x reference)
//
#include <hip/hip_runtime.h>
#include <stdint.h>

typedef _Float16 f16;
typedef _Float16 half8 __attribute__((ext_vector_type(8)));
typedef float f32x4 __attribute__((ext_vector_type(4)));
typedef unsigned long long u64;

#define T_SEQ 1024
#define N_RECUR 32
#define NWG 40

// ws layout
#define WS_H0 4096            // [2 parity][64 kblk][32 b][8] f16 = 65536 B
#define WS_H1 (4096 + 65536)
#define WS_E  (4096 + 131072) // ring[4][96 kblk][32 b][8] f16 = 196608 B
#define ESLOT 24576           // f16 elements per ring slot

static __device__ __forceinline__ half8 ld_h8(const f16* p) {
    u64 lo = __hip_atomic_load((u64*)p,     __ATOMIC_RELAXED, __HIP_MEMORY_SCOPE_AGENT);
    u64 hi = __hip_atomic_load((u64*)p + 1, __ATOMIC_RELAXED, __HIP_MEMORY_SCOPE_AGENT);
    union { u64 q[2]; half8 v; } u; u.q[0] = lo; u.q[1] = hi; return u.v;
}

static __device__ __forceinline__ void poll_ge(uint32_t* flags, uint32_t need,
                                               int lane, int nflags) {
    int idx = lane < nflags ? lane : 0;
    while (true) {
        uint32_t v = __hip_atomic_load(flags + idx, __ATOMIC_RELAXED,
                                       __HIP_MEMORY_SCOPE_AGENT);
        if (__all(v >= need)) break;
        __builtin_amdgcn_s_sleep(1);
    }
    __builtin_amdgcn_sched_barrier(0);
}

__global__ void __launch_bounds__(256, 1)
lstm_fused(const int* __restrict__ x, const float* __restrict__ emb,
           const float* __restrict__ w_ih0, const float* __restrict__ w_hh0,
           const float* __restrict__ b_ih0, const float* __restrict__ b_hh0,
           const float* __restrict__ w_ih1, const float* __restrict__ w_hh1,
           const float* __restrict__ b_ih1, const float* __restrict__ b_hh1,
           const float* __restrict__ fc_w, const float* __restrict__ fc_b,
           float* __restrict__ out, uint8_t* __restrict__ ws)
{
    const int wg   = blockIdx.x;
    const int tid  = threadIdx.x;
    const int lane = tid & 63;
    const int wq   = tid >> 6;         // wave 0..3
    const int r8   = lane & 15;
    const int kgb  = lane >> 4;        // k-group 0..3 (8 elems each)

    uint32_t* flags = (uint32_t*)ws;
    f16* h0buf = (f16*)(ws + WS_H0);
    f16* h1buf = (f16*)(ws + WS_H1);
    f16* ering = (f16*)(ws + WS_E);

    // ================= e-producer wgs =================
    if (wg >= N_RECUR) {
        const int p = wg - N_RECUR;    // 0..7, owns batch rows 4p..4p+3
        auto gather = [&](int t) {
#pragma unroll
            for (int rr = 0; rr < 2; ++rr) {
                int idx = rr * 256 + tid;
                if (idx < 384) {
                    int bl = idx / 96, seg = idx % 96, k0 = seg * 8;
                    int b = p * 4 + bl;
                    int tok = x[b * T_SEQ + t];
                    const float* src = emb + (size_t)tok * 768 + k0;
                    float4 v0 = ((const float4*)src)[0];
                    float4 v1 = ((const float4*)src)[1];
                    union { half8 h; u64 q[2]; } u;
                    u.h[0] = (f16)v0.x; u.h[1] = (f16)v0.y; u.h[2] = (f16)v0.z; u.h[3] = (f16)v0.w;
                    u.h[4] = (f16)v1.x; u.h[5] = (f16)v1.y; u.h[6] = (f16)v1.z; u.h[7] = (f16)v1.w;
                    u64* dst = (u64*)(ering + (size_t)(t & 3) * ESLOT + ((size_t)seg * 32 + b) * 8);
                    __hip_atomic_store(dst,     u.q[0], __ATOMIC_RELAXED, __HIP_MEMORY_SCOPE_AGENT);
                    __hip_atomic_store(dst + 1, u.q[1], __ATOMIC_RELAXED, __HIP_MEMORY_SCOPE_AGENT);
                }
            }
        };
        gather(0); gather(1); gather(2);
        asm volatile("s_waitcnt vmcnt(0)" ::: "memory");
        __syncthreads();
        if (tid == 0)
            __hip_atomic_store(flags + wg, 3u, __ATOMIC_RELAXED, __HIP_MEMORY_SCOPE_AGENT);
        for (int s = 0;; ++s) {
            int g = s + 3;
            if (g >= T_SEQ) {
                if (tid == 0)
                    __hip_atomic_store(flags + wg, (uint32_t)(T_SEQ + 8),
                                       __ATOMIC_RELAXED, __HIP_MEMORY_SCOPE_AGENT);
                break;
            }
            poll_ge(flags, (uint32_t)(s + 1), lane, 16);   // L0 done reading slot
            gather(g);
            asm volatile("s_waitcnt vmcnt(0)" ::: "memory");
            __syncthreads();
            if (tid == 0)
                __hip_atomic_store(flags + wg, (uint32_t)(s + 4),
                                   __ATOMIC_RELAXED, __HIP_MEMORY_SCOPE_AGENT);
        }
        return;
    }

    // ================= recurrence wgs =================
    const bool isL0 = (wg < 16);
    const int wloc  = isL0 ? wg : wg - 16;
    const int NKC   = isL0 ? 40 : 32;  // K = 768+512 (e in ring) -> e:24,h0:16 | h0:16,h1:16

    __shared__ float accs[32][130];
    __shared__ float bias_lds[128];
    __shared__ f16   hsh2[4][32][8];
    __shared__ f16   stage[16384];     // FC epilogue (wg 0 only)

    // ---- weights -> register fragments (f16) ----
    half8 breg[2][40];
#pragma unroll
    for (int i = 0; i < 2; ++i) {
        int nl = (2 * wq + i) * 16 + r8;          // local gate row 0..127
        int g = nl >> 5, jj = nl & 31;
        int grow = (g << 9) + wloc * 32 + jj;     // global gate row
        if (isL0) {
#pragma unroll
            for (int kc = 0; kc < 40; ++kc) {
                int k = kc * 32 + kgb * 8;
                const float* src = (k < 768) ? (w_ih0 + (size_t)grow * 768 + k)
                                             : (w_hh0 + (size_t)grow * 512 + (k - 768));
                half8 v;
#pragma unroll
                for (int e = 0; e < 8; ++e) v[e] = (f16)src[e];
                breg[i][kc] = v;
            }
        } else {
#pragma unroll
            for (int kc = 0; kc < 32; ++kc) {
                int k = kc * 32 + kgb * 8;
                const float* src = (k < 512) ? (w_ih1 + (size_t)grow * 512 + k)
                                             : (w_hh1 + (size_t)grow * 512 + (k - 512));
                half8 v;
#pragma unroll
                for (int e = 0; e < 8; ++e) v[e] = (f16)src[e];
                breg[i][kc] = v;
            }
        }
    }
    if (tid < 128) {
        int grow = ((tid >> 5) << 9) + wloc * 32 + (tid & 31);
        bias_lds[tid] = isL0 ? (b_ih0[grow] + b_hh0[grow]) : (b_ih1[grow] + b_hh1[grow]);
    }

    // ---- init: zero own slice of parity-1 plane ----
    if (wq == 0) {
        u64* z = (u64*)((isL0 ? h0buf : h1buf) + 16384) + (size_t)wloc * 256;
#pragma unroll
        for (int q = 0; q < 4; ++q)
            __hip_atomic_store(z + lane * 4 + q, 0ULL, __ATOMIC_RELAXED, __HIP_MEMORY_SCOPE_AGENT);
    }
    asm volatile("s_waitcnt vmcnt(0)" ::: "memory");
    __syncthreads();
    if (tid == 0)
        __hip_atomic_store(flags + wg, 1u, __ATOMIC_RELAXED, __HIP_MEMORY_SCOPE_AGENT);

    float c0 = 0.f, c1 = 0.f, c2 = 0.f, c3 = 0.f;
    const int jj = tid & 31, bq = tid >> 5;

    for (int s = 0; s <= T_SEQ; ++s) {
        poll_ge(flags, (uint32_t)(s + 1), lane, NWG);
        const bool active = isL0 ? (s < T_SEQ) : (s >= 1);
        if (active) {
            f32x4 acc00 = {0,0,0,0}, acc01 = {0,0,0,0}, acc10 = {0,0,0,0}, acc11 = {0,0,0,0};
            const f16* pe  = ering + (size_t)(s & 3) * ESLOT;          // e_s (L0)
            const f16* ph0 = h0buf + (size_t)((s + 1) & 1) * 16384;    // h0_{s-1}
            const f16* ph1 = h1buf + (size_t)(s & 1) * 16384;          // h1_{s-2} (L1)
            if (isL0) {
#pragma unroll
                for (int kc = 0; kc < 40; ++kc) {
                    const f16* base = (kc < 24) ? pe : ph0;
                    int kb = (kc < 24) ? kc * 4 : (kc - 24) * 4;
                    half8 a0 = ld_h8(base + ((size_t)(kb + kgb) * 32 + r8) * 8);
                    half8 a1 = ld_h8(base + ((size_t)(kb + kgb) * 32 + 16 + r8) * 8);
                    acc00 = __builtin_amdgcn_mfma_f32_16x16x32_f16(a0, breg[0][kc], acc00, 0, 0, 0);
                    acc01 = __builtin_amdgcn_mfma_f32_16x16x32_f16(a0, breg[1][kc], acc01, 0, 0, 0);
                    acc10 = __builtin_amdgcn_mfma_f32_16x16x32_f16(a1, breg[0][kc], acc10, 0, 0, 0);
                    acc11 = __builtin_amdgcn_mfma_f32_16x16x32_f16(a1, breg[1][kc], acc11, 0, 0, 0);
                }
            } else {
#pragma unroll
                for (int kc = 0; kc < 32; ++kc) {
                    const f16* base = (kc < 16) ? ph0 : ph1;
                    int kb = (kc < 16) ? kc * 4 : (kc - 16) * 4;
                    half8 a0 = ld_h8(base + ((size_t)(kb + kgb) * 32 + r8) * 8);
                    half8 a1 = ld_h8(base + ((size_t)(kb + kgb) * 32 + 16 + r8) * 8);
                    acc00 = __builtin_amdgcn_mfma_f32_16x16x32_f16(a0, breg[0][kc], acc00, 0, 0, 0);
                    acc01 = __builtin_amdgcn_mfma_f32_16x16x32_f16(a0, breg[1][kc], acc01, 0, 0, 0);
                    acc10 = __builtin_amdgcn_mfma_f32_16x16x32_f16(a1, breg[0][kc], acc10, 0, 0, 0);
                    acc11 = __builtin_amdgcn_mfma_f32_16x16x32_f16(a1, breg[1][kc], acc11, 0, 0, 0);
                }
            }
            const int cr = (lane >> 4) * 4;            // C/D: row=(lane>>4)*4+q (batch)
            const int cc0 = 2 * wq * 16 + r8;          //      col=lane&15 (gate row)
#pragma unroll
            for (int q = 0; q < 4; ++q) {
                accs[cr + q][cc0]           = acc00[q];
                accs[cr + q][cc0 + 16]      = acc01[q];
                accs[16 + cr + q][cc0]      = acc10[q];
                accs[16 + cr + q][cc0 + 16] = acc11[q];
            }
        }
        __syncthreads();
        if (active) {
            float cs[4] = {c0, c1, c2, c3};
#pragma unroll
            for (int ii = 0; ii < 4; ++ii) {
                int b = bq * 4 + ii;
                float gi = accs[b][jj]       + bias_lds[jj];
                float gf = accs[b][32 + jj]  + bias_lds[32 + jj];
                float gg = accs[b][64 + jj]  + bias_lds[64 + jj];
                float go = accs[b][96 + jj]  + bias_lds[96 + jj];
                float si = __builtin_amdgcn_rcpf(1.f + __expf(-gi));
                float sf = __builtin_amdgcn_rcpf(1.f + __expf(-gf));
                float so = __builtin_amdgcn_rcpf(1.f + __expf(-go));
                float tg = 1.f - 2.f * __builtin_amdgcn_rcpf(__expf(2.f * gg) + 1.f);
                cs[ii] = sf * cs[ii] + si * tg;
                float hv = so * (1.f - 2.f * __builtin_amdgcn_rcpf(__expf(2.f * cs[ii]) + 1.f));
                hsh2[jj >> 3][b][jj & 7] = (f16)hv;
            }
            c0 = cs[0]; c1 = cs[1]; c2 = cs[2]; c3 = cs[3];
        }
        __syncthreads();
        if (active && wq == 0) {
            f16* plane = isL0 ? (h0buf + (size_t)(s & 1) * 16384)
                              : (h1buf + (size_t)((s + 1) & 1) * 16384);
            u64* dst = (u64*)plane + (size_t)wloc * 256 + lane * 4;
            const u64* srcp = (const u64*)hsh2 + lane * 4;
            u64 q0 = srcp[0], q1 = srcp[1], q2 = srcp[2], q3 = srcp[3];
            __hip_atomic_store(dst,     q0, __ATOMIC_RELAXED, __HIP_MEMORY_SCOPE_AGENT);
            __hip_atomic_store(dst + 1, q1, __ATOMIC_RELAXED, __HIP_MEMORY_SCOPE_AGENT);
            __hip_atomic_store(dst + 2, q2, __ATOMIC_RELAXED, __HIP_MEMORY_SCOPE_AGENT);
            __hip_atomic_store(dst + 3, q3, __ATOMIC_RELAXED, __HIP_MEMORY_SCOPE_AGENT);
        }
        asm volatile("s_waitcnt vmcnt(0)" ::: "memory");
        if (tid == 0)
            __hip_atomic_store(flags + wg, (uint32_t)(s + 2),
                               __ATOMIC_RELAXED, __HIP_MEMORY_SCOPE_AGENT);
    }

    // ---------- FC epilogue (wg 0): h2 = h1_{1023}, parity 1 ----------
    if (wg == 0) {
        poll_ge(flags, (uint32_t)(T_SEQ + 2), lane, N_RECUR);
        u64* h2g = (u64*)(h1buf + 16384);
        u64* stg = (u64*)stage;
        for (int i = tid; i < 4096; i += 256)
            stg[i] = __hip_atomic_load(h2g + i, __ATOMIC_RELAXED, __HIP_MEMORY_SCOPE_AGENT);
        __syncthreads();
        if (tid < 160) {
            int b = tid / 5, n = tid % 5;
            const f16* h2 = stage;
            float fsum = fc_b[n];
#pragma unroll 8
            for (int j = 0; j < 512; ++j)
                fsum += (float)h2[((j >> 3) * 32 + b) * 8 + (j & 7)] * fc_w[n * 512 + j];
            out[b * 5 + n] = fsum;
        }
    }
}

extern "C" void kernel_launch(void* const* d_in, const int* in_sizes, int n_in,
                              void* d_out, int out_size, void* d_ws, size_t ws_size,
                              hipStream_t stream) {
    (void)in_sizes; (void)n_in; (void)out_size; (void)ws_size;
    hipMemsetAsync(d_ws, 0, 4096, stream);     // flags must start at 0
    lstm_fused<<<dim3(NWG), dim3(256), 0, stream>>>(
        (const int*)d_in[0],  (const float*)d_in[1],
        (const float*)d_in[2], (const float*)d_in[3],
        (const float*)d_in[4], (const float*)d_in[5],
        (const float*)d_in[6], (const float*)d_in[7],
        (const float*)d_in[8], (const float*)d_in[9],
        (const float*)d_in[10], (const float*)d_in[11],
        (float*)d_out, (uint8_t*)d_ws);
}

// Round 4
// 4616.094 us; speedup vs baseline: 2.6230x; 2.6230x over previous
//
#include <hip/hip_runtime.h>
#include <stdint.h>

typedef _Float16 f16;
typedef _Float16 half8 __attribute__((ext_vector_type(8)));
typedef float f32x4 __attribute__((ext_vector_type(4)));
typedef unsigned long long u64;

#define T_SEQ 1024
#define NWG 136            // 64 L0 + 64 L1 + 8 e-producers
#define FS 4               // flag stride in u32 -> 16B spacing

// ws layout
#define WS_H0 4096         // [2 parity][64 kblk][32 b][8] f16 = 65536 B
#define WS_H1 (4096 + 65536)
#define WS_E  (4096 + 131072)   // ring[4][96 kblk][32 b][8] f16
#define ESLOT 24576

static __device__ __forceinline__ half8 ld_h8(const f16* p) {
    u64 lo = __hip_atomic_load((const u64*)p,     __ATOMIC_RELAXED, __HIP_MEMORY_SCOPE_AGENT);
    u64 hi = __hip_atomic_load((const u64*)p + 1, __ATOMIC_RELAXED, __HIP_MEMORY_SCOPE_AGENT);
    union { u64 q[2]; half8 v; } u; u.q[0] = lo; u.q[1] = hi; return u.v;
}

// wave-local: wait until flags[base..base+n) >= need (n<=64)
static __device__ __forceinline__ void poll64(uint32_t* flags, int base, int n,
                                              uint32_t need, int lane) {
    int idx = base + (lane < n ? lane : 0);
    while (true) {
        uint32_t v = __hip_atomic_load(flags + idx * FS, __ATOMIC_RELAXED,
                                       __HIP_MEMORY_SCOPE_AGENT);
        if (__all(v >= need)) break;
        __builtin_amdgcn_s_sleep(1);
    }
    __builtin_amdgcn_sched_barrier(0);
}

// wave-local: wait until flags[0..128) >= need
static __device__ __forceinline__ void poll128(uint32_t* flags, uint32_t need, int lane) {
    while (true) {
        uint32_t a = __hip_atomic_load(flags + lane * FS, __ATOMIC_RELAXED,
                                       __HIP_MEMORY_SCOPE_AGENT);
        uint32_t b = __hip_atomic_load(flags + (lane + 64) * FS, __ATOMIC_RELAXED,
                                       __HIP_MEMORY_SCOPE_AGENT);
        if (__all((a >= need) && (b >= need))) break;
        __builtin_amdgcn_s_sleep(1);
    }
    __builtin_amdgcn_sched_barrier(0);
}

__global__ void __launch_bounds__(256, 1)
lstm_fused(const int* __restrict__ x, const float* __restrict__ emb,
           const float* __restrict__ w_ih0, const float* __restrict__ w_hh0,
           const float* __restrict__ b_ih0, const float* __restrict__ b_hh0,
           const float* __restrict__ w_ih1, const float* __restrict__ w_hh1,
           const float* __restrict__ b_ih1, const float* __restrict__ b_hh1,
           const float* __restrict__ fc_w, const float* __restrict__ fc_b,
           float* __restrict__ out, uint8_t* __restrict__ ws)
{
    const int wg   = blockIdx.x;
    const int tid  = threadIdx.x;
    const int lane = tid & 63;
    const int wave = tid >> 6;
    const int mtile = wave >> 1;       // batch half (0/1)
    const int ntile = wave & 1;        // gate-col half (0/1)
    const int r8   = lane & 15;
    const int kgb  = lane >> 4;

    uint32_t* flags = (uint32_t*)ws;
    f16* h0buf = (f16*)(ws + WS_H0);
    f16* h1buf = (f16*)(ws + WS_H1);
    f16* ering = (f16*)(ws + WS_E);

    // ================= e-producer wgs (128..135) =================
    if (wg >= 128) {
        const int p = wg - 128;        // owns batch rows 4p..4p+3
        auto gather = [&](int t) {
#pragma unroll
            for (int rr = 0; rr < 2; ++rr) {
                int idx = rr * 256 + tid;
                if (idx < 384) {
                    int bl = idx / 96, seg = idx % 96, k0 = seg * 8;
                    int b = p * 4 + bl;
                    int tok = x[b * T_SEQ + t];
                    const float* src = emb + (size_t)tok * 768 + k0;
                    float4 v0 = ((const float4*)src)[0];
                    float4 v1 = ((const float4*)src)[1];
                    union { half8 h; u64 q[2]; } u;
                    u.h[0] = (f16)v0.x; u.h[1] = (f16)v0.y; u.h[2] = (f16)v0.z; u.h[3] = (f16)v0.w;
                    u.h[4] = (f16)v1.x; u.h[5] = (f16)v1.y; u.h[6] = (f16)v1.z; u.h[7] = (f16)v1.w;
                    u64* dst = (u64*)(ering + (size_t)(t & 3) * ESLOT + ((size_t)seg * 32 + b) * 8);
                    __hip_atomic_store(dst,     u.q[0], __ATOMIC_RELAXED, __HIP_MEMORY_SCOPE_AGENT);
                    __hip_atomic_store(dst + 1, u.q[1], __ATOMIC_RELAXED, __HIP_MEMORY_SCOPE_AGENT);
                }
            }
        };
        gather(0); gather(1); gather(2);
        asm volatile("s_waitcnt vmcnt(0)" ::: "memory");
        __syncthreads();
        if (tid == 0)
            __hip_atomic_store(flags + wg * FS, 3u, __ATOMIC_RELAXED, __HIP_MEMORY_SCOPE_AGENT);
        for (int s = 0;; ++s) {
            int g = s + 3;
            if (g >= T_SEQ) {
                if (tid == 0)
                    __hip_atomic_store(flags + wg * FS, (uint32_t)(T_SEQ + 8),
                                       __ATOMIC_RELAXED, __HIP_MEMORY_SCOPE_AGENT);
                break;
            }
            poll64(flags, 0, 64, (uint32_t)(s + 1), lane);  // L0 done reading slot (s-1)&3
            gather(g);
            asm volatile("s_waitcnt vmcnt(0)" ::: "memory");
            __syncthreads();
            if (tid == 0)
                __hip_atomic_store(flags + wg * FS, (uint32_t)(s + 4),
                                   __ATOMIC_RELAXED, __HIP_MEMORY_SCOPE_AGENT);
        }
        return;
    }

    // ================= recurrence wgs =================
    const bool isL0 = (wg < 64);
    const int wloc  = isL0 ? wg : wg - 64;
    const int j0    = wloc * 8;        // owned h-columns

    __shared__ float accs[32][33];
    __shared__ float bias_lds[32];
    __shared__ f16   hsh[32][8];
    __shared__ f16   stage[16384];     // FC epilogue (wg 0)

    // ---- weights -> register fragments ----
    const int nrow = ((ntile * 2 + (r8 >> 3)) << 9) + j0 + (r8 & 7);
    half8 breg[40];
    if (isL0) {
#pragma unroll
        for (int kc = 0; kc < 40; ++kc) {
            int k = kc * 32 + kgb * 8;
            const float* src = (k < 768) ? (w_ih0 + (size_t)nrow * 768 + k)
                                         : (w_hh0 + (size_t)nrow * 512 + (k - 768));
            half8 v;
#pragma unroll
            for (int e = 0; e < 8; ++e) v[e] = (f16)src[e];
            breg[kc] = v;
        }
    } else {
#pragma unroll
        for (int kc = 0; kc < 32; ++kc) {
            int k = kc * 32 + kgb * 8;
            const float* src = (k < 512) ? (w_ih1 + (size_t)nrow * 512 + k)
                                         : (w_hh1 + (size_t)nrow * 512 + (k - 512));
            half8 v;
#pragma unroll
            for (int e = 0; e < 8; ++e) v[e] = (f16)src[e];
            breg[kc] = v;
        }
    }
    if (tid < 32) {
        int n2 = ((tid >> 3) << 9) + j0 + (tid & 7);
        bias_lds[tid] = isL0 ? (b_ih0[n2] + b_hh0[n2]) : (b_ih1[n2] + b_hh1[n2]);
    }

    // ---- zero parity-1 planes (wgs 0..31 cover both) ----
    {
        int gid = wg * 256 + tid;
        if (gid < 8192) {
            u64* base = (gid < 4096) ? (u64*)(h0buf + 16384) : (u64*)(h1buf + 16384);
            __hip_atomic_store(base + (gid & 4095), 0ULL,
                               __ATOMIC_RELAXED, __HIP_MEMORY_SCOPE_AGENT);
        }
    }
    asm volatile("s_waitcnt vmcnt(0)" ::: "memory");
    __syncthreads();
    if (tid == 0)
        __hip_atomic_store(flags + wg * FS, isL0 ? 1u : 2u,
                           __ATOMIC_RELAXED, __HIP_MEMORY_SCOPE_AGENT);

    float cst = 0.f;
    const int tb = tid >> 3, tj = tid & 7;
    const int arow = mtile * 16 + r8;

    const int sBeg = isL0 ? 0 : 1;
    const int sEnd = isL0 ? T_SEQ : T_SEQ + 1;   // exclusive

    for (int s = sBeg; s < sEnd; ++s) {
        f32x4 acc0 = {0.f, 0.f, 0.f, 0.f}, acc1 = {0.f, 0.f, 0.f, 0.f};
        if (isL0) {
            poll64(flags, 128, 8, (uint32_t)(s + 1), lane);       // e_s ready
            const f16* pe = ering + (size_t)(s & 3) * ESLOT;
            half8 ea[24];
#pragma unroll
            for (int kc = 0; kc < 24; ++kc)
                ea[kc] = ld_h8(pe + (((size_t)(kc * 4 + kgb) * 32 + arow) << 3));
            poll128(flags, (uint32_t)(s + 1), lane);              // h planes safe
            const f16* ph = h0buf + (size_t)((s + 1) & 1) * 16384;
#pragma unroll
            for (int kc = 0; kc < 24; ++kc) {
                if (kc & 1) acc1 = __builtin_amdgcn_mfma_f32_16x16x32_f16(ea[kc], breg[kc], acc1, 0, 0, 0);
                else        acc0 = __builtin_amdgcn_mfma_f32_16x16x32_f16(ea[kc], breg[kc], acc0, 0, 0, 0);
            }
#pragma unroll
            for (int kc = 24; kc < 40; ++kc) {
                half8 a = ld_h8(ph + ((((size_t)(kc - 24) * 4 + kgb) * 32 + arow) << 3));
                if (kc & 1) acc1 = __builtin_amdgcn_mfma_f32_16x16x32_f16(a, breg[kc], acc1, 0, 0, 0);
                else        acc0 = __builtin_amdgcn_mfma_f32_16x16x32_f16(a, breg[kc], acc0, 0, 0, 0);
            }
        } else {
            poll64(flags, 0, 64, (uint32_t)(s + 1), lane);        // h0_{s-1} ready
            const f16* pa = h0buf + (size_t)((s + 1) & 1) * 16384;
            half8 av[16];
#pragma unroll
            for (int kc = 0; kc < 16; ++kc)
                av[kc] = ld_h8(pa + (((size_t)(kc * 4 + kgb) * 32 + arow) << 3));
            poll64(flags, 64, 64, (uint32_t)(s + 1), lane);       // h1_{s-2} ready
            const f16* pb = h1buf + (size_t)(s & 1) * 16384;
#pragma unroll
            for (int kc = 0; kc < 16; ++kc) {
                if (kc & 1) acc1 = __builtin_amdgcn_mfma_f32_16x16x32_f16(av[kc], breg[kc], acc1, 0, 0, 0);
                else        acc0 = __builtin_amdgcn_mfma_f32_16x16x32_f16(av[kc], breg[kc], acc0, 0, 0, 0);
            }
#pragma unroll
            for (int kc = 16; kc < 32; ++kc) {
                half8 a = ld_h8(pb + ((((size_t)(kc - 16) * 4 + kgb) * 32 + arow) << 3));
                if (kc & 1) acc1 = __builtin_amdgcn_mfma_f32_16x16x32_f16(a, breg[kc], acc1, 0, 0, 0);
                else        acc0 = __builtin_amdgcn_mfma_f32_16x16x32_f16(a, breg[kc], acc0, 0, 0, 0);
            }
        }
        {
            f32x4 accv = acc0 + acc1;
            const int crow0 = mtile * 16 + (lane >> 4) * 4;   // C/D: row=(lane>>4)*4+q
            const int ccol  = ntile * 16 + r8;                //      col=lane&15
#pragma unroll
            for (int q = 0; q < 4; ++q) accs[crow0 + q][ccol] = accv[q];
        }
        __syncthreads();
        {
            float gi = accs[tb][tj]      + bias_lds[tj];
            float gf = accs[tb][8 + tj]  + bias_lds[8 + tj];
            float gg = accs[tb][16 + tj] + bias_lds[16 + tj];
            float go = accs[tb][24 + tj] + bias_lds[24 + tj];
            float si = __builtin_amdgcn_rcpf(1.f + __expf(-gi));
            float sf = __builtin_amdgcn_rcpf(1.f + __expf(-gf));
            float so = __builtin_amdgcn_rcpf(1.f + __expf(-go));
            float tg = 1.f - 2.f * __builtin_amdgcn_rcpf(__expf(2.f * gg) + 1.f);
            cst = sf * cst + si * tg;
            float hv = so * (1.f - 2.f * __builtin_amdgcn_rcpf(__expf(2.f * cst) + 1.f));
            hsh[tb][tj] = (f16)hv;
        }
        __syncthreads();
        if (tid < 32) {                 // 16B per lane, wg slice contiguous
            f16* plane = isL0 ? (h0buf + (size_t)(s & 1) * 16384)
                              : (h1buf + (size_t)((s + 1) & 1) * 16384);
            u64* dst = (u64*)plane + ((size_t)wloc * 32 + tid) * 2;
            const u64* srcp = (const u64*)hsh + tid * 2;
            u64 q0 = srcp[0], q1 = srcp[1];
            __hip_atomic_store(dst,     q0, __ATOMIC_RELAXED, __HIP_MEMORY_SCOPE_AGENT);
            __hip_atomic_store(dst + 1, q1, __ATOMIC_RELAXED, __HIP_MEMORY_SCOPE_AGENT);
        }
        if (tid == 0) {
            asm volatile("s_waitcnt vmcnt(0)" ::: "memory");
            __hip_atomic_store(flags + wg * FS, (uint32_t)(s + 2),
                               __ATOMIC_RELAXED, __HIP_MEMORY_SCOPE_AGENT);
        }
    }

    // ---------- FC epilogue (wg 0): h2 = h1_{1023}, parity 1 ----------
    if (wg == 0) {
        poll64(flags, 64, 64, (uint32_t)(T_SEQ + 2), lane);
        u64* h2g = (u64*)(h1buf + 16384);
        u64* stg = (u64*)stage;
        for (int i = tid; i < 4096; i += 256)
            stg[i] = __hip_atomic_load(h2g + i, __ATOMIC_RELAXED, __HIP_MEMORY_SCOPE_AGENT);
        __syncthreads();
        if (tid < 160) {
            int b = tid / 5, n = tid % 5;
            const f16* h2 = stage;
            float fsum = fc_b[n];
#pragma unroll 8
            for (int j = 0; j < 512; ++j)
                fsum += (float)h2[((j >> 3) * 32 + b) * 8 + (j & 7)] * fc_w[n * 512 + j];
            out[b * 5 + n] = fsum;
        }
    }
}

extern "C" void kernel_launch(void* const* d_in, const int* in_sizes, int n_in,
                              void* d_out, int out_size, void* d_ws, size_t ws_size,
                              hipStream_t stream) {
    (void)in_sizes; (void)n_in; (void)out_size; (void)ws_size;
    hipMemsetAsync(d_ws, 0, 4096, stream);     // flags start at 0
    lstm_fused<<<dim3(NWG), dim3(256), 0, stream>>>(
        (const int*)d_in[0],  (const float*)d_in[1],
        (const float*)d_in[2], (const float*)d_in[3],
        (const float*)d_in[4], (const float*)d_in[5],
        (const float*)d_in[6], (const float*)d_in[7],
        (const float*)d_in[8], (const float*)d_in[9],
        (const float*)d_in[10], (const float*)d_in[11],
        (float*)d_out, (uint8_t*)d_ws);
}

// Round 5
// 4253.988 us; speedup vs baseline: 2.8463x; 1.0851x over previous
//
#include <hip/hip_runtime.h>
#include <stdint.h>

typedef _Float16 f16;
typedef _Float16 half8 __attribute__((ext_vector_type(8)));
typedef float f32x4 __attribute__((ext_vector_type(4)));
typedef unsigned long long u64;

#define T_SEQ 1024
#define NWG 136            // 64 L0 + 64 L1 + 8 e-producers
#define FS 32              // flag stride in u32 -> 128B (own L3 line)

// ws layout
#define WS_FLAGS_BYTES (NWG * 128)
#define WS_H0 32768        // 4 planes x [64 kblk][32 b][8] f16 = 4 x 32768 B
#define WS_H1 (WS_H0 + 131072)      // 2 planes x 32768 B
#define WS_E  (WS_H1 + 65536)       // ring[4][96 kblk][32 b][8] f16
#define ESLOT 24576
#define HPLANE 16384       // f16 elements per h plane

static __device__ __forceinline__ half8 ld_h8(const f16* p) {
    u64 lo = __hip_atomic_load((const u64*)p,     __ATOMIC_RELAXED, __HIP_MEMORY_SCOPE_AGENT);
    u64 hi = __hip_atomic_load((const u64*)p + 1, __ATOMIC_RELAXED, __HIP_MEMORY_SCOPE_AGENT);
    union { u64 q[2]; half8 v; } u; u.q[0] = lo; u.q[1] = hi; return u.v;
}

// wait until flags[base..base+n) >= need (n<=64), wave-parallel
static __device__ __forceinline__ void poll64(uint32_t* flags, int base, int n,
                                              uint32_t need, int lane) {
    int idx = (base + (lane < n ? lane : 0)) * FS;
    while (true) {
        uint32_t v = __hip_atomic_load(flags + idx, __ATOMIC_RELAXED,
                                       __HIP_MEMORY_SCOPE_AGENT);
        if (__all(v >= need)) break;
        __builtin_amdgcn_s_sleep(1);
    }
    __builtin_amdgcn_sched_barrier(0);
}

// L0's fused dep poll: L0 flags >= needA, L1 flags >= needB
static __device__ __forceinline__ void poll2(uint32_t* flags, uint32_t needA,
                                             uint32_t needB, int lane) {
    while (true) {
        uint32_t a = __hip_atomic_load(flags + lane * FS, __ATOMIC_RELAXED,
                                       __HIP_MEMORY_SCOPE_AGENT);
        uint32_t b = __hip_atomic_load(flags + (64 + lane) * FS, __ATOMIC_RELAXED,
                                       __HIP_MEMORY_SCOPE_AGENT);
        if (__all((a >= needA) && (b >= needB))) break;
        __builtin_amdgcn_s_sleep(1);
    }
    __builtin_amdgcn_sched_barrier(0);
}

__global__ void __launch_bounds__(256, 1)
lstm_fused(const int* __restrict__ x, const float* __restrict__ emb,
           const float* __restrict__ w_ih0, const float* __restrict__ w_hh0,
           const float* __restrict__ b_ih0, const float* __restrict__ b_hh0,
           const float* __restrict__ w_ih1, const float* __restrict__ w_hh1,
           const float* __restrict__ b_ih1, const float* __restrict__ b_hh1,
           const float* __restrict__ fc_w, const float* __restrict__ fc_b,
           float* __restrict__ out, uint8_t* __restrict__ ws)
{
    const int wg   = blockIdx.x;
    const int tid  = threadIdx.x;
    const int lane = tid & 63;
    const int wave = tid >> 6;
    const int mtile = wave >> 1;       // batch half (0/1)
    const int ntile = wave & 1;        // gate-col half (0/1)
    const int r8   = lane & 15;
    const int kgb  = lane >> 4;

    uint32_t* flags = (uint32_t*)ws;
    f16* h0buf = (f16*)(ws + WS_H0);   // 4-deep ring
    f16* h1buf = (f16*)(ws + WS_H1);   // 2-deep ring
    f16* ering = (f16*)(ws + WS_E);    // 4-deep ring

    // ================= e-producer wgs (128..135) =================
    if (wg >= 128) {
        const int p = wg - 128;        // owns batch rows 4p..4p+3
        auto gather = [&](int t) {
#pragma unroll
            for (int rr = 0; rr < 2; ++rr) {
                int idx = rr * 256 + tid;
                if (idx < 384) {
                    int bl = idx / 96, seg = idx % 96, k0 = seg * 8;
                    int b = p * 4 + bl;
                    int tok = x[b * T_SEQ + t];
                    const float* src = emb + (size_t)tok * 768 + k0;
                    float4 v0 = ((const float4*)src)[0];
                    float4 v1 = ((const float4*)src)[1];
                    union { half8 h; u64 q[2]; } u;
                    u.h[0] = (f16)v0.x; u.h[1] = (f16)v0.y; u.h[2] = (f16)v0.z; u.h[3] = (f16)v0.w;
                    u.h[4] = (f16)v1.x; u.h[5] = (f16)v1.y; u.h[6] = (f16)v1.z; u.h[7] = (f16)v1.w;
                    u64* dst = (u64*)(ering + (size_t)(t & 3) * ESLOT + ((size_t)seg * 32 + b) * 8);
                    __hip_atomic_store(dst,     u.q[0], __ATOMIC_RELAXED, __HIP_MEMORY_SCOPE_AGENT);
                    __hip_atomic_store(dst + 1, u.q[1], __ATOMIC_RELAXED, __HIP_MEMORY_SCOPE_AGENT);
                }
            }
        };
        gather(0); gather(1); gather(2);
        asm volatile("s_waitcnt vmcnt(0)" ::: "memory");
        __syncthreads();
        if (tid == 0)
            __hip_atomic_store(flags + wg * FS, 3u, __ATOMIC_RELAXED, __HIP_MEMORY_SCOPE_AGENT);
        for (int s = 0;; ++s) {
            int g = s + 3;
            if (g >= T_SEQ) {
                if (tid == 0)
                    __hip_atomic_store(flags + wg * FS, (uint32_t)(T_SEQ + 8),
                                       __ATOMIC_RELAXED, __HIP_MEMORY_SCOPE_AGENT);
                break;
            }
            poll64(flags, 0, 64, (uint32_t)(s + 1), lane);  // L0 done reading slot g&3
            gather(g);
            asm volatile("s_waitcnt vmcnt(0)" ::: "memory");
            __syncthreads();
            if (tid == 0)
                __hip_atomic_store(flags + wg * FS, (uint32_t)(s + 4),
                                   __ATOMIC_RELAXED, __HIP_MEMORY_SCOPE_AGENT);
        }
        return;
    }

    // ================= recurrence wgs =================
    const bool isL0 = (wg < 64);
    const int wloc  = isL0 ? wg : wg - 64;
    const int j0    = wloc * 8;        // owned h-columns

    __shared__ float accs[32][33];
    __shared__ float bias_lds[32];
    __shared__ f16   hsh[32][8];
    __shared__ f16   stage[16384];     // FC epilogue (wg 0)

    // ---- weights -> register fragments ----
    const int nrow = ((ntile * 2 + (r8 >> 3)) << 9) + j0 + (r8 & 7);
    half8 breg[40];
    if (isL0) {
#pragma unroll
        for (int kc = 0; kc < 40; ++kc) {
            int k = kc * 32 + kgb * 8;
            const float* src = (k < 768) ? (w_ih0 + (size_t)nrow * 768 + k)
                                         : (w_hh0 + (size_t)nrow * 512 + (k - 768));
            half8 v;
#pragma unroll
            for (int e = 0; e < 8; ++e) v[e] = (f16)src[e];
            breg[kc] = v;
        }
    } else {
#pragma unroll
        for (int kc = 0; kc < 32; ++kc) {
            int k = kc * 32 + kgb * 8;
            const float* src = (k < 512) ? (w_ih1 + (size_t)nrow * 512 + k)
                                         : (w_hh1 + (size_t)nrow * 512 + (k - 512));
            half8 v;
#pragma unroll
            for (int e = 0; e < 8; ++e) v[e] = (f16)src[e];
            breg[kc] = v;
        }
    }
    if (tid < 32) {
        int n2 = ((tid >> 3) << 9) + j0 + (tid & 7);
        bias_lds[tid] = isL0 ? (b_ih0[n2] + b_hh0[n2]) : (b_ih1[n2] + b_hh1[n2]);
    }

    // ---- zero-init: h0 plane 3 + h1 plane 1 (wgs 0..31 cover 8192 u64) ----
    {
        int gid = wg * 256 + tid;
        if (gid < 8192) {
            u64* base = (gid < 4096) ? (u64*)(h0buf + 3 * HPLANE)
                                     : (u64*)(h1buf + 1 * HPLANE);
            __hip_atomic_store(base + (gid & 4095), 0ULL,
                               __ATOMIC_RELAXED, __HIP_MEMORY_SCOPE_AGENT);
        }
    }
    asm volatile("s_waitcnt vmcnt(0)" ::: "memory");
    __syncthreads();
    if (tid == 0)
        __hip_atomic_store(flags + wg * FS, isL0 ? 1u : 2u,
                           __ATOMIC_RELAXED, __HIP_MEMORY_SCOPE_AGENT);

    float cst = 0.f;
    const int tb = tid >> 3, tj = tid & 7;
    const int arow = mtile * 16 + r8;

    const int sBeg = isL0 ? 0 : 1;
    const int sEnd = isL0 ? T_SEQ : T_SEQ + 1;   // exclusive

    for (int s = sBeg; s < sEnd; ++s) {
        f32x4 acc0 = {0.f, 0.f, 0.f, 0.f}, acc1 = {0.f, 0.f, 0.f, 0.f};
        if (isL0) {
            // e_s ready? (producers run 3 ahead; usually immediate)
            poll64(flags, 128, 8, (uint32_t)(s + 1), lane);
            const f16* pe = ering + (size_t)(s & 3) * ESLOT;
            half8 ea[24];
#pragma unroll
            for (int kc = 0; kc < 24; ++kc)
                ea[kc] = ld_h8(pe + (((size_t)(kc * 4 + kgb) * 32 + arow) << 3));
            // data dep: all L0 >= s+1 (h0_{s-1} ready)
            // anti-dep: all L1 >= s-1 (plane s&3 free) -- 2 steps of slack
            poll2(flags, (uint32_t)(s + 1), (uint32_t)(s > 0 ? s - 1 : 0), lane);
            const f16* ph = h0buf + (size_t)((s + 3) & 3) * HPLANE;   // h0_{s-1}
#pragma unroll
            for (int kc = 0; kc < 24; ++kc) {
                if (kc & 1) acc1 = __builtin_amdgcn_mfma_f32_16x16x32_f16(ea[kc], breg[kc], acc1, 0, 0, 0);
                else        acc0 = __builtin_amdgcn_mfma_f32_16x16x32_f16(ea[kc], breg[kc], acc0, 0, 0, 0);
            }
#pragma unroll
            for (int kc = 24; kc < 40; ++kc) {
                half8 a = ld_h8(ph + ((((size_t)(kc - 24) * 4 + kgb) * 32 + arow) << 3));
                if (kc & 1) acc1 = __builtin_amdgcn_mfma_f32_16x16x32_f16(a, breg[kc], acc1, 0, 0, 0);
                else        acc0 = __builtin_amdgcn_mfma_f32_16x16x32_f16(a, breg[kc], acc0, 0, 0, 0);
            }
        } else {
            // data dep: h0_{s-1} ready (all L0 >= s+1)
            poll64(flags, 0, 64, (uint32_t)(s + 1), lane);
            const f16* pa = h0buf + (size_t)((s + 3) & 3) * HPLANE;   // h0_{s-1}
            half8 av[16];
#pragma unroll
            for (int kc = 0; kc < 16; ++kc)
                av[kc] = ld_h8(pa + (((size_t)(kc * 4 + kgb) * 32 + arow) << 3));
            // own-layer: all L1 >= s+1 (h1_{s-2} ready, plane s&1 free)
            poll64(flags, 64, 64, (uint32_t)(s + 1), lane);
            const f16* pb = h1buf + (size_t)(s & 1) * HPLANE;         // h1_{s-2}
#pragma unroll
            for (int kc = 0; kc < 16; ++kc) {
                if (kc & 1) acc1 = __builtin_amdgcn_mfma_f32_16x16x32_f16(av[kc], breg[kc], acc1, 0, 0, 0);
                else        acc0 = __builtin_amdgcn_mfma_f32_16x16x32_f16(av[kc], breg[kc], acc0, 0, 0, 0);
            }
#pragma unroll
            for (int kc = 16; kc < 32; ++kc) {
                half8 a = ld_h8(pb + ((((size_t)(kc - 16) * 4 + kgb) * 32 + arow) << 3));
                if (kc & 1) acc1 = __builtin_amdgcn_mfma_f32_16x16x32_f16(a, breg[kc], acc1, 0, 0, 0);
                else        acc0 = __builtin_amdgcn_mfma_f32_16x16x32_f16(a, breg[kc], acc0, 0, 0, 0);
            }
        }
        {
            f32x4 accv = acc0 + acc1;
            const int crow0 = mtile * 16 + (lane >> 4) * 4;   // C/D: row=(lane>>4)*4+q
            const int ccol  = ntile * 16 + r8;                //      col=lane&15
#pragma unroll
            for (int q = 0; q < 4; ++q) accs[crow0 + q][ccol] = accv[q];
        }
        __syncthreads();
        {
            float gi = accs[tb][tj]      + bias_lds[tj];
            float gf = accs[tb][8 + tj]  + bias_lds[8 + tj];
            float gg = accs[tb][16 + tj] + bias_lds[16 + tj];
            float go = accs[tb][24 + tj] + bias_lds[24 + tj];
            float si = __builtin_amdgcn_rcpf(1.f + __expf(-gi));
            float sf = __builtin_amdgcn_rcpf(1.f + __expf(-gf));
            float so = __builtin_amdgcn_rcpf(1.f + __expf(-go));
            float tg = 1.f - 2.f * __builtin_amdgcn_rcpf(__expf(2.f * gg) + 1.f);
            cst = sf * cst + si * tg;
            float hv = so * (1.f - 2.f * __builtin_amdgcn_rcpf(__expf(2.f * cst) + 1.f));
            hsh[tb][tj] = (f16)hv;
        }
        __syncthreads();
        if (tid < 32) {                 // 16B per lane, wg slice contiguous
            f16* plane = isL0 ? (h0buf + (size_t)(s & 3) * HPLANE)         // h0_s
                              : (h1buf + (size_t)((s + 1) & 1) * HPLANE);  // h1_{s-1}
            u64* dst = (u64*)plane + ((size_t)wloc * 32 + tid) * 2;
            const u64* srcp = (const u64*)hsh + tid * 2;
            u64 q0 = srcp[0], q1 = srcp[1];
            __hip_atomic_store(dst,     q0, __ATOMIC_RELAXED, __HIP_MEMORY_SCOPE_AGENT);
            __hip_atomic_store(dst + 1, q1, __ATOMIC_RELAXED, __HIP_MEMORY_SCOPE_AGENT);
        }
        if (tid == 0) {
            asm volatile("s_waitcnt vmcnt(0)" ::: "memory");
            __hip_atomic_store(flags + wg * FS, (uint32_t)(s + 2),
                               __ATOMIC_RELAXED, __HIP_MEMORY_SCOPE_AGENT);
        }
    }

    // ---------- FC epilogue (wg 0): h2 = h1_{1023} = plane (T-1)&1 = 1 ----------
    if (wg == 0) {
        poll64(flags, 64, 64, (uint32_t)(T_SEQ + 2), lane);
        u64* h2g = (u64*)(h1buf + 1 * HPLANE);
        u64* stg = (u64*)stage;
        for (int i = tid; i < 4096; i += 256)
            stg[i] = __hip_atomic_load(h2g + i, __ATOMIC_RELAXED, __HIP_MEMORY_SCOPE_AGENT);
        __syncthreads();
        if (tid < 160) {
            int b = tid / 5, n = tid % 5;
            const f16* h2 = stage;
            float fsum = fc_b[n];
#pragma unroll 8
            for (int j = 0; j < 512; ++j)
                fsum += (float)h2[((j >> 3) * 32 + b) * 8 + (j & 7)] * fc_w[n * 512 + j];
            out[b * 5 + n] = fsum;
        }
    }
}

extern "C" void kernel_launch(void* const* d_in, const int* in_sizes, int n_in,
                              void* d_out, int out_size, void* d_ws, size_t ws_size,
                              hipStream_t stream) {
    (void)in_sizes; (void)n_in; (void)out_size; (void)ws_size;
    hipMemsetAsync(d_ws, 0, WS_FLAGS_BYTES, stream);   // flags start at 0
    lstm_fused<<<dim3(NWG), dim3(256), 0, stream>>>(
        (const int*)d_in[0],  (const float*)d_in[1],
        (const float*)d_in[2], (const float*)d_in[3],
        (const float*)d_in[4], (const float*)d_in[5],
        (const float*)d_in[6], (const float*)d_in[7],
        (const float*)d_in[8], (const float*)d_in[9],
        (const float*)d_in[10], (const float*)d_in[11],
        (float*)d_out, (uint8_t*)d_ws);
}